// Round 20
// baseline (131.685 us; speedup 1.0000x reference)
//
#include <hip/hip_runtime.h>
#include <hip/hip_fp16.h>

#define NNODES 50000
#define NEDGES 800000
#define NSLOPE 0.2f
#define NB2 782        // buckets of 64 dsts
#define BCAP2 1280     // ssrc slots per bucket
#define CSRB 256       // CSR sort blocks
#define EPB 3125       // edges per CSR block
#define PAH 136        // A-tile LDS pitch in halves (16B-aligned rows)

typedef _Float16 half8v __attribute__((ext_vector_type(8)));
typedef float floatx4 __attribute__((ext_vector_type(4)));

__device__ __forceinline__ float lrelu(float x) { return x > 0.f ? x : NSLOPE * x; }

// 8 halves (uint4) FMA into f32 acc via v_fma_mix_f32
__device__ __forceinline__ void fmamix8(float* acc, uint4 v, float w) {
    asm("v_fma_mix_f32 %0, %1, %2, %0 op_sel:[0,0,0] op_sel_hi:[0,1,0]" : "+v"(acc[0]) : "v"(w), "v"(v.x));
    asm("v_fma_mix_f32 %0, %1, %2, %0 op_sel:[0,1,0] op_sel_hi:[0,1,0]" : "+v"(acc[1]) : "v"(w), "v"(v.x));
    asm("v_fma_mix_f32 %0, %1, %2, %0 op_sel:[0,0,0] op_sel_hi:[0,1,0]" : "+v"(acc[2]) : "v"(w), "v"(v.y));
    asm("v_fma_mix_f32 %0, %1, %2, %0 op_sel:[0,1,0] op_sel_hi:[0,1,0]" : "+v"(acc[3]) : "v"(w), "v"(v.y));
    asm("v_fma_mix_f32 %0, %1, %2, %0 op_sel:[0,0,0] op_sel_hi:[0,1,0]" : "+v"(acc[4]) : "v"(w), "v"(v.z));
    asm("v_fma_mix_f32 %0, %1, %2, %0 op_sel:[0,1,0] op_sel_hi:[0,1,0]" : "+v"(acc[5]) : "v"(w), "v"(v.z));
    asm("v_fma_mix_f32 %0, %1, %2, %0 op_sel:[0,0,0] op_sel_hi:[0,1,0]" : "+v"(acc[6]) : "v"(w), "v"(v.w));
    asm("v_fma_mix_f32 %0, %1, %2, %0 op_sel:[0,1,0] op_sel_hi:[0,1,0]" : "+v"(acc[7]) : "v"(w), "v"(v.w));
}

// ---------------- W -> MFMA B-fragment layout (f16), one-time tiny kernel ----------------
__global__ __launch_bounds__(256) void wconv_kernel(const float* __restrict__ W1,
                                                    const float* __restrict__ W2,
                                                    __half* __restrict__ Wf1,
                                                    __half* __restrict__ Wf2) {
    int tid = blockIdx.x * 256 + threadIdx.x;
    if (tid < 2048) {
        int l = tid & 63, t = (tid >> 6) & 7, ks = tid >> 9;
        int col = t * 16 + (l & 15), kq = l >> 4;
        __half* dst = Wf1 + (size_t)tid * 8;
#pragma unroll
        for (int j = 0; j < 8; j++)
            dst[j] = __float2half(W1[(ks * 32 + kq * 8 + j) * 128 + col]);
    } else if (tid < 3072) {
        int u = tid - 2048;
        int l = u & 63, t = (u >> 6) & 3, ks = u >> 8;
        int col = t * 16 + (l & 15), kq = l >> 4;
        __half* dst = Wf2 + (size_t)u * 8;
#pragma unroll
        for (int j = 0; j < 8; j++)
            dst[j] = __float2half(W2[(ks * 32 + kq * 8 + j) * 64 + col]);
    }
}

// ---------------- MFMA GEMM + attention-dot body (A dtype templated) ----------------
template<int NCOL, int HEADS, typename AT>
__device__ void gemm_mfma_body(int bid, __half* __restrict__ Ah,
                               const AT* __restrict__ A, const __half* __restrict__ Wf,
                               const float* __restrict__ atts, const float* __restrict__ attd,
                               __half* __restrict__ H, float* __restrict__ as_,
                               float* __restrict__ ad_, int nrows) {
    constexpr int NT = NCOL / 16;
    constexpr int TPH = NT / HEADS;
    int t = threadIdx.x;
    long r0 = (long)bid * 64;
    long abase = r0 * 128, alimit = (long)nrows * 128;
#pragma unroll
    for (int i = 0; i < 8; i++) {
        int off = i * 1024 + t * 4;
        uint2 pk = make_uint2(0, 0);
        if (abase + off < alimit) {
            if constexpr (sizeof(AT) == 4) {
                float4 v = *(const float4*)&A[abase + off];
                __half2 h0 = __floats2half2_rn(v.x, v.y);
                __half2 h1 = __floats2half2_rn(v.z, v.w);
                pk = make_uint2(*(unsigned*)&h0, *(unsigned*)&h1);
            } else {
                pk = *(const uint2*)&A[abase + off];
            }
        }
        *(uint2*)&Ah[(off >> 7) * PAH + (off & 127)] = pk;
    }
    __syncthreads();

    int w = t >> 6, l = t & 63;
    int i16 = l & 15, q = l >> 4;
    floatx4 acc[NT];
#pragma unroll
    for (int n = 0; n < NT; n++) acc[n] = (floatx4)0.f;
    const half8v* wf = (const half8v*)Wf;
#pragma unroll
    for (int ks = 0; ks < 4; ks++) {
        half8v afrag = *(const half8v*)&Ah[(w * 16 + i16) * PAH + ks * 32 + q * 8];
#pragma unroll
        for (int n = 0; n < NT; n++) {
            half8v bfrag = wf[(ks * NT + n) * 64 + l];
            acc[n] = __builtin_amdgcn_mfma_f32_16x16x32_f16(afrag, bfrag, acc[n], 0, 0, 0);
        }
    }
    long rb = r0 + w * 16 + q * 4;
#pragma unroll
    for (int n = 0; n < NT; n++) {
#pragma unroll
        for (int reg = 0; reg < 4; reg++) {
            long row = rb + reg;
            if (row < nrows) H[row * NCOL + n * 16 + i16] = __float2half(acc[n][reg]);
        }
    }
    float ps[4][HEADS], pd[4][HEADS];
#pragma unroll
    for (int reg = 0; reg < 4; reg++)
#pragma unroll
        for (int h = 0; h < HEADS; h++) { ps[reg][h] = 0.f; pd[reg][h] = 0.f; }
#pragma unroll
    for (int n = 0; n < NT; n++) {
        float sa = atts[n * 16 + i16], da = attd[n * 16 + i16];
        int h = n / TPH;
#pragma unroll
        for (int reg = 0; reg < 4; reg++) {
            ps[reg][h] += acc[n][reg] * sa;
            pd[reg][h] += acc[n][reg] * da;
        }
    }
#pragma unroll
    for (int reg = 0; reg < 4; reg++)
#pragma unroll
        for (int h = 0; h < HEADS; h++)
#pragma unroll
            for (int m = 1; m < 16; m <<= 1) {
                ps[reg][h] += __shfl_xor(ps[reg][h], m);
                pd[reg][h] += __shfl_xor(pd[reg][h], m);
            }
    if (i16 < HEADS) {
        int h = i16;
#pragma unroll
        for (int reg = 0; reg < 4; reg++) {
            long row = rb + reg;
            if (row < nrows) {
                float pv = 0.f, dv = 0.f;
#pragma unroll
                for (int hh = 0; hh < HEADS; hh++) { if (hh == h) { pv = ps[reg][hh]; dv = pd[reg][hh]; } }
                as_[row * HEADS + h] = pv;
                ad_[row * HEADS + h] = dv;
            }
        }
    }
}

// ---------------- fused: in-LDS counting sort (blocks 0..255) | MFMA GEMM1 ----------------
__global__ __launch_bounds__(256) void fused_csr_gemm1_kernel(
    const int* __restrict__ ei, unsigned* __restrict__ priv,
    int* __restrict__ cnt_mtx, int* __restrict__ lofs_mtx,
    const float* __restrict__ A, const __half* __restrict__ Wf1,
    const float* __restrict__ atts, const float* __restrict__ attd,
    __half* __restrict__ H, float* __restrict__ as_, float* __restrict__ ad_, int nrows) {
    __shared__ __align__(16) char smem[21760];
    if (blockIdx.x >= CSRB) {
        gemm_mfma_body<128, 4, float>(blockIdx.x - CSRB, (__half*)smem, A, Wf1, atts, attd,
                                      H, as_, ad_, nrows);
        return;
    }
    int* hist = (int*)smem;
    int* lofs = hist + 1024;
    int* sbuf = lofs + 1024;
    unsigned* ebuf = (unsigned*)(sbuf + 256);
    int tid = threadIdx.x;
    for (int i = tid; i < 1024; i += 256) hist[i] = 0;
    __syncthreads();
    int e0 = blockIdx.x * EPB;
    int dreg[13];
#pragma unroll
    for (int i = 0; i < 13; i++) {
        int e = e0 + i * 256 + tid;
        dreg[i] = (e < e0 + EPB) ? ei[NEDGES + e] : -1;
        if (dreg[i] >= 0) atomicAdd(&hist[dreg[i] >> 6], 1);
    }
    __syncthreads();
    int t4 = tid * 4;
    int a0 = hist[t4], a1 = hist[t4 + 1], a2 = hist[t4 + 2], a3 = hist[t4 + 3];
    int p1 = a0 + a1, p2 = p1 + a2, p3 = p2 + a3;
    sbuf[tid] = p3;
    __syncthreads();
    for (int off = 1; off < 256; off <<= 1) {
        int v = (tid >= off) ? sbuf[tid - off] : 0;
        __syncthreads();
        sbuf[tid] += v;
        __syncthreads();
    }
    int base = (tid > 0) ? sbuf[tid - 1] : 0;
    lofs[t4] = base; lofs[t4 + 1] = base + a0; lofs[t4 + 2] = base + p1; lofs[t4 + 3] = base + p2;
#pragma unroll
    for (int j = 0; j < 4; j++) {
        int i = t4 + j;
        if (i < NB2) {
            cnt_mtx[(long)blockIdx.x * NB2 + i] = hist[i];
            lofs_mtx[(long)blockIdx.x * NB2 + i] = lofs[i];
        }
    }
    hist[t4] = 0; hist[t4 + 1] = 0; hist[t4 + 2] = 0; hist[t4 + 3] = 0;
    __syncthreads();
#pragma unroll
    for (int i = 0; i < 13; i++) {
        if (dreg[i] >= 0) {
            int e = e0 + i * 256 + tid;
            int s = ei[e];
            int b = dreg[i] >> 6;
            int r = atomicAdd(&hist[b], 1);
            ebuf[lofs[b] + r] = (unsigned)s | ((unsigned)(dreg[i] & 63) << 16);
        }
    }
    __syncthreads();
    unsigned* seg = priv + (long)blockIdx.x * EPB;
    for (int i = tid; i < EPB; i += 256) seg[i] = ebuf[i];
}

// ---------------- consumer: rank into LDS, dense dump -> dst-grouped ssrc ----------------
__global__ __launch_bounds__(256) void consumer_kernel(
    const unsigned* __restrict__ priv, const int* __restrict__ cnt_mtx,
    const int* __restrict__ lofs_mtx, int* __restrict__ ssrc,
    int* __restrict__ offs, int* __restrict__ ends) {
    __shared__ int dcnt[64], dbase[64], dcur[64];
    __shared__ unsigned ebuf[BCAP2];
    int b = blockIdx.x, tid = threadIdx.x;
    if (tid < 64) dcnt[tid] = 0;
    int cnt = cnt_mtx[(long)tid * NB2 + b];
    int lof = lofs_mtx[(long)tid * NB2 + b];
    const unsigned* seg = priv + (long)tid * EPB + lof;
    __syncthreads();
    for (int k = 0; k < cnt; k++) {
        unsigned v = seg[k];
        atomicAdd(&dcnt[(v >> 16) & 63], 1);
    }
    __syncthreads();
    if (tid < 64) {
        int v = dcnt[tid], p = v;
#pragma unroll
        for (int off = 1; off < 64; off <<= 1) {
            int u = __shfl_up(p, off);
            if (tid >= off) p += u;
        }
        dbase[tid] = p - v;
        dcur[tid] = p - v;
    }
    __syncthreads();
    for (int k = 0; k < cnt; k++) {
        unsigned v = seg[k];
        int dl = (v >> 16) & 63;
        int r = atomicAdd(&dcur[dl], 1);
        if (r < BCAP2) ebuf[r] = v & 0xFFFFu;
    }
    __syncthreads();
    int obase = b * BCAP2;
    int n = dbase[63] + dcnt[63];
    if (n > BCAP2) n = BCAP2;
    for (int i = tid; i < n; i += 256) ssrc[obase + i] = (int)ebuf[i];
    if (tid < 64) {
        int d = b * 64 + tid;
        if (d < NNODES) {
            int s0 = dbase[tid], e1 = s0 + dcnt[tid];
            if (s0 > BCAP2) s0 = BCAP2;
            if (e1 > BCAP2) e1 = BCAP2;
            offs[d] = obase + s0;
            ends[d] = obase + e1;
        }
    }
}

// ---------------- standalone MFMA GEMM (layer 2, fp16 A) ----------------
template<int NCOL, int HEADS, typename AT>
__global__ __launch_bounds__(256) void gemm_att_kernel(
    const AT* __restrict__ A, const __half* __restrict__ Wf,
    const float* __restrict__ atts, const float* __restrict__ attd,
    __half* __restrict__ H, float* __restrict__ as_, float* __restrict__ ad_,
    int nrows) {
    __shared__ __align__(16) __half Ah[64 * PAH];
    gemm_mfma_body<NCOL, HEADS, AT>(blockIdx.x, Ah, A, Wf, atts, attd, H, as_, ad_, nrows);
}

// ---------------- gather: r18 chunk loop + next-chunk row-load prefetch ----------------
// Identical semantics to r18; only change: next chunk's NV row loads (vB) issue
// BEFORE current chunk's FMAs, hiding one memory latency per chunk.
template<int HEADS, int NCOL, int LRELU, typename OT>
__global__ __launch_bounds__(256) void gather_kernel(
    const int* __restrict__ ssrc, const int* __restrict__ offs,
    const int* __restrict__ ends, const float* __restrict__ as_,
    const float* __restrict__ ad_, const __half* __restrict__ H,
    const float* __restrict__ bias, OT* __restrict__ out, int n) {
    constexpr int CHUNK = 64 / HEADS;   // 16 (L1) or 64 (L2)
    constexpr int LPE = NCOL / 8;       // lanes per row: 16 or 8
    constexpr int EPI = 64 / LPE;       // edges per VMEM instr: 4 or 8
    constexpr int NV = CHUNK / EPI;     // VMEM loads per chunk: 4 or 8
    int wave = (blockIdx.x * blockDim.x + threadIdx.x) >> 6;
    if (wave >= n) return;
    int lane = threadIdx.x & 63;
    int d = wave;
    int sub = lane / LPE;
    int c = (lane % LPE) * 8;
    int hc = (HEADS == 1) ? 0 : (c >> 5);
    int SB = hc * CHUNK;
    int pe = (HEADS == 1) ? lane : (lane % CHUNK);
    int ph = (HEADS == 1) ? 0 : (lane / CHUNK);
    float ad_p = ad_[d * HEADS + ph];
    float acc[8];
#pragma unroll
    for (int i = 0; i < 8; i++) acc[i] = 0.f;
    float dsum = 0.f;
    int start = offs[d], end = ends[d];

    int base = start;
    int m = end - base; if (m > CHUNK) m = CHUNK;
    int sv = 0; float wv = 0.f;
    uint4 vA[NV];
    if (m > 0) {
        if (pe < m) {
            sv = ssrc[base + pe];
            wv = __expf(lrelu(as_[sv * HEADS + ph] + ad_p));
        }
        dsum += wv;
#pragma unroll
        for (int k = 0; k < NV; k++) {
            int idx = k * EPI + sub;
            int cl = idx < m ? idx : m - 1;
            int s = __shfl(sv, SB + cl);
            vA[k] = *(const uint4*)&H[(long)s * NCOL + c];
        }
    }
    while (m > 0) {
        int nbase = base + CHUNK;
        int nm = end - nbase; if (nm > CHUNK) nm = CHUNK;
        int svn = 0; float wvn = 0.f;
        uint4 vB[NV];
        if (nm > 0) {   // produce next chunk: weights + row-load issue (before FMAs)
            if (pe < nm) {
                svn = ssrc[nbase + pe];
                wvn = __expf(lrelu(as_[svn * HEADS + ph] + ad_p));
            }
            dsum += wvn;
#pragma unroll
            for (int k = 0; k < NV; k++) {
                int idx = k * EPI + sub;
                int cl = idx < nm ? idx : nm - 1;
                int s = __shfl(svn, SB + cl);
                vB[k] = *(const uint4*)&H[(long)s * NCOL + c];
            }
        }
        // consume current chunk
#pragma unroll
        for (int k = 0; k < NV; k++) {
            int idx = k * EPI + sub;
            int cl = idx < m ? idx : m - 1;
            float w = __shfl(wv, SB + cl);
            if (idx >= m) w = 0.f;
            fmamix8(acc, vA[k], w);
        }
        if (nm <= 0) break;
        sv = svn; wv = wvn; m = nm; base = nbase;
#pragma unroll
        for (int k = 0; k < NV; k++) vA[k] = vB[k];
    }

    if (HEADS == 1) {
#pragma unroll
        for (int msk = 1; msk < 64; msk <<= 1) dsum += __shfl_xor(dsum, msk);
    } else {
#pragma unroll
        for (int msk = 1; msk < 16; msk <<= 1) dsum += __shfl_xor(dsum, msk);
        dsum = __shfl(dsum, SB);
    }
#pragma unroll
    for (int msk = LPE; msk < 64; msk <<= 1) {
#pragma unroll
        for (int i = 0; i < 8; i++) acc[i] += __shfl_xor(acc[i], msk);
    }
    {
        float wself = __expf(lrelu(as_[d * HEADS + hc] + ad_[d * HEADS + hc]));
        dsum += wself;
        uint4 vs = *(const uint4*)&H[(long)d * NCOL + c];
        fmamix8(acc, vs, wself);
    }
    float inv = 1.f / (dsum + 1e-16f);
    if (lane < LPE) {
        float r[8];
#pragma unroll
        for (int i = 0; i < 8; i++) {
            r[i] = acc[i] * inv + bias[c + i];
            if (LRELU) r[i] = lrelu(r[i]);
        }
        if constexpr (sizeof(OT) == 2) {
            __half2 q0 = __floats2half2_rn(r[0], r[1]);
            __half2 q1 = __floats2half2_rn(r[2], r[3]);
            __half2 q2 = __floats2half2_rn(r[4], r[5]);
            __half2 q3 = __floats2half2_rn(r[6], r[7]);
            uint4 pk = make_uint4(*(unsigned*)&q0, *(unsigned*)&q1, *(unsigned*)&q2, *(unsigned*)&q3);
            *(uint4*)&out[(long)d * NCOL + c] = pk;
        } else {
            *(float4*)&out[(long)d * NCOL + c] = make_float4(r[0], r[1], r[2], r[3]);
            *(float4*)&out[(long)d * NCOL + c + 4] = make_float4(r[4], r[5], r[6], r[7]);
        }
    }
}

static inline int nblk(long total) { return (int)((total + 255) / 256); }

extern "C" void kernel_launch(void* const* d_in, const int* in_sizes, int n_in,
                              void* d_out, int out_size, void* d_ws, size_t ws_size,
                              hipStream_t stream) {
    const float* x    = (const float*)d_in[0];
    const int*   ei   = (const int*)d_in[1];   // [2, NEDGES]
    const float* W1   = (const float*)d_in[2];
    const float* as1w = (const float*)d_in[3];
    const float* ad1w = (const float*)d_in[4];
    const float* b1   = (const float*)d_in[5];
    const float* W2   = (const float*)d_in[6];
    const float* as2w = (const float*)d_in[7];
    const float* ad2w = (const float*)d_in[8];
    const float* b2   = (const float*)d_in[9];
    float* out = (float*)d_out;

    char* wsb = (char*)d_ws;
    size_t o = 0;
    __half* h1    = (__half*)(wsb + o); o += (size_t)NNODES * 128 * 2;   // 12.8 MB; h2 aliases
    __half* x2h   = (__half*)(wsb + o); o += (size_t)NNODES * 128 * 2;   // 12.8 MB
    float* a_src1 = (float*)(wsb + o);  o += (size_t)NNODES * 4 * 4;
    float* a_dst1 = (float*)(wsb + o);  o += (size_t)NNODES * 4 * 4;
    float* a_src2 = (float*)(wsb + o);  o += (size_t)NNODES * 4;
    float* a_dst2 = (float*)(wsb + o);  o += (size_t)NNODES * 4;
    int* offs    = (int*)(wsb + o); o += (size_t)NNODES * 4;
    int* ends    = (int*)(wsb + o); o += (size_t)NNODES * 4;
    int* ssrc    = (int*)(wsb + o); o += (size_t)NB2 * BCAP2 * 4;        // 4.0 MB
    unsigned* priv = (unsigned*)(wsb + o); o += (size_t)CSRB * EPB * 4;  // 3.2 MB
    int* cnt_mtx  = (int*)(wsb + o); o += (size_t)CSRB * NB2 * 4;        // 0.8 MB
    int* lofs_mtx = (int*)(wsb + o); o += (size_t)CSRB * NB2 * 4;        // 0.8 MB
    __half* Wf1  = (__half*)(wsb + o); o += (size_t)2048 * 8 * 2;        // 32 KB
    __half* Wf2  = (__half*)(wsb + o); o += (size_t)1024 * 8 * 2;        // 16 KB
    __half* h2 = h1;

    const int GB = (NNODES + 63) / 64;     // 782

    // ---- W -> fragment-layout f16 (one-time) ----
    wconv_kernel<<<12, 256, 0, stream>>>(W1, W2, Wf1, Wf2);

    // ---- CSR build (in-LDS sort, dense dump) + MFMA GEMM1, fused ----
    fused_csr_gemm1_kernel<<<CSRB + GB, 256, 0, stream>>>(
        ei, priv, cnt_mtx, lofs_mtx, x, Wf1, as1w, ad1w, h1, a_src1, a_dst1, NNODES);
    consumer_kernel<<<NB2, 256, 0, stream>>>(priv, cnt_mtx, lofs_mtx, ssrc, offs, ends);

    // ---- layer 1 gather (fp16 output) ----
    gather_kernel<4, 128, 1, __half><<<nblk((long)NNODES * 64), 256, 0, stream>>>(
        ssrc, offs, ends, a_src1, a_dst1, h1, b1, x2h, NNODES);

    // ---- layer 2 (fp16 A) ----
    gemm_att_kernel<64, 1, __half><<<GB, 256, 0, stream>>>(
        x2h, Wf2, as2w, ad2w, h2, a_src2, a_dst2, NNODES);
    gather_kernel<1, 64, 0, float><<<nblk((long)NNODES * 64), 256, 0, stream>>>(
        ssrc, offs, ends, a_src2, a_dst2, h2, b2, out, NNODES);
}

// Round 21
// 116.864 us; speedup vs baseline: 1.1268x; 1.1268x over previous
//
#include <hip/hip_runtime.h>
#include <hip/hip_fp16.h>

#define NNODES 50000
#define NEDGES 800000
#define NSLOPE 0.2f
#define NB2 782        // buckets of 64 dsts
#define BCAP2 1280     // ssrc slots per bucket
#define CSRB 256       // CSR sort blocks
#define EPB 3125       // edges per CSR block
#define PAH 136        // A-tile LDS pitch in halves (16B-aligned rows)

typedef _Float16 half8v __attribute__((ext_vector_type(8)));
typedef float floatx4 __attribute__((ext_vector_type(4)));

__device__ __forceinline__ float lrelu(float x) { return x > 0.f ? x : NSLOPE * x; }

// 8 halves (uint4) FMA into f32 acc via v_fma_mix_f32
__device__ __forceinline__ void fmamix8(float* acc, uint4 v, float w) {
    asm("v_fma_mix_f32 %0, %1, %2, %0 op_sel:[0,0,0] op_sel_hi:[0,1,0]" : "+v"(acc[0]) : "v"(w), "v"(v.x));
    asm("v_fma_mix_f32 %0, %1, %2, %0 op_sel:[0,1,0] op_sel_hi:[0,1,0]" : "+v"(acc[1]) : "v"(w), "v"(v.x));
    asm("v_fma_mix_f32 %0, %1, %2, %0 op_sel:[0,0,0] op_sel_hi:[0,1,0]" : "+v"(acc[2]) : "v"(w), "v"(v.y));
    asm("v_fma_mix_f32 %0, %1, %2, %0 op_sel:[0,1,0] op_sel_hi:[0,1,0]" : "+v"(acc[3]) : "v"(w), "v"(v.y));
    asm("v_fma_mix_f32 %0, %1, %2, %0 op_sel:[0,0,0] op_sel_hi:[0,1,0]" : "+v"(acc[4]) : "v"(w), "v"(v.z));
    asm("v_fma_mix_f32 %0, %1, %2, %0 op_sel:[0,1,0] op_sel_hi:[0,1,0]" : "+v"(acc[5]) : "v"(w), "v"(v.z));
    asm("v_fma_mix_f32 %0, %1, %2, %0 op_sel:[0,0,0] op_sel_hi:[0,1,0]" : "+v"(acc[6]) : "v"(w), "v"(v.w));
    asm("v_fma_mix_f32 %0, %1, %2, %0 op_sel:[0,1,0] op_sel_hi:[0,1,0]" : "+v"(acc[7]) : "v"(w), "v"(v.w));
}

// ---------------- W -> MFMA B-fragment layout (f16), one-time tiny kernel ----------------
__global__ __launch_bounds__(256) void wconv_kernel(const float* __restrict__ W1,
                                                    const float* __restrict__ W2,
                                                    __half* __restrict__ Wf1,
                                                    __half* __restrict__ Wf2) {
    int tid = blockIdx.x * 256 + threadIdx.x;
    if (tid < 2048) {
        int l = tid & 63, t = (tid >> 6) & 7, ks = tid >> 9;
        int col = t * 16 + (l & 15), kq = l >> 4;
        __half* dst = Wf1 + (size_t)tid * 8;
#pragma unroll
        for (int j = 0; j < 8; j++)
            dst[j] = __float2half(W1[(ks * 32 + kq * 8 + j) * 128 + col]);
    } else if (tid < 3072) {
        int u = tid - 2048;
        int l = u & 63, t = (u >> 6) & 3, ks = u >> 8;
        int col = t * 16 + (l & 15), kq = l >> 4;
        __half* dst = Wf2 + (size_t)u * 8;
#pragma unroll
        for (int j = 0; j < 8; j++)
            dst[j] = __float2half(W2[(ks * 32 + kq * 8 + j) * 64 + col]);
    }
}

// ---------------- MFMA GEMM + attention-dot body (A dtype templated) ----------------
template<int NCOL, int HEADS, typename AT>
__device__ void gemm_mfma_body(int bid, __half* __restrict__ Ah,
                               const AT* __restrict__ A, const __half* __restrict__ Wf,
                               const float* __restrict__ atts, const float* __restrict__ attd,
                               __half* __restrict__ H, float* __restrict__ as_,
                               float* __restrict__ ad_, int nrows) {
    constexpr int NT = NCOL / 16;
    constexpr int TPH = NT / HEADS;
    int t = threadIdx.x;
    long r0 = (long)bid * 64;
    long abase = r0 * 128, alimit = (long)nrows * 128;
#pragma unroll
    for (int i = 0; i < 8; i++) {
        int off = i * 1024 + t * 4;
        uint2 pk = make_uint2(0, 0);
        if (abase + off < alimit) {
            if constexpr (sizeof(AT) == 4) {
                float4 v = *(const float4*)&A[abase + off];
                __half2 h0 = __floats2half2_rn(v.x, v.y);
                __half2 h1 = __floats2half2_rn(v.z, v.w);
                pk = make_uint2(*(unsigned*)&h0, *(unsigned*)&h1);
            } else {
                pk = *(const uint2*)&A[abase + off];
            }
        }
        *(uint2*)&Ah[(off >> 7) * PAH + (off & 127)] = pk;
    }
    __syncthreads();

    int w = t >> 6, l = t & 63;
    int i16 = l & 15, q = l >> 4;
    floatx4 acc[NT];
#pragma unroll
    for (int n = 0; n < NT; n++) acc[n] = (floatx4)0.f;
    const half8v* wf = (const half8v*)Wf;
#pragma unroll
    for (int ks = 0; ks < 4; ks++) {
        half8v afrag = *(const half8v*)&Ah[(w * 16 + i16) * PAH + ks * 32 + q * 8];
#pragma unroll
        for (int n = 0; n < NT; n++) {
            half8v bfrag = wf[(ks * NT + n) * 64 + l];
            acc[n] = __builtin_amdgcn_mfma_f32_16x16x32_f16(afrag, bfrag, acc[n], 0, 0, 0);
        }
    }
    long rb = r0 + w * 16 + q * 4;
#pragma unroll
    for (int n = 0; n < NT; n++) {
#pragma unroll
        for (int reg = 0; reg < 4; reg++) {
            long row = rb + reg;
            if (row < nrows) H[row * NCOL + n * 16 + i16] = __float2half(acc[n][reg]);
        }
    }
    float ps[4][HEADS], pd[4][HEADS];
#pragma unroll
    for (int reg = 0; reg < 4; reg++)
#pragma unroll
        for (int h = 0; h < HEADS; h++) { ps[reg][h] = 0.f; pd[reg][h] = 0.f; }
#pragma unroll
    for (int n = 0; n < NT; n++) {
        float sa = atts[n * 16 + i16], da = attd[n * 16 + i16];
        int h = n / TPH;
#pragma unroll
        for (int reg = 0; reg < 4; reg++) {
            ps[reg][h] += acc[n][reg] * sa;
            pd[reg][h] += acc[n][reg] * da;
        }
    }
#pragma unroll
    for (int reg = 0; reg < 4; reg++)
#pragma unroll
        for (int h = 0; h < HEADS; h++)
#pragma unroll
            for (int m = 1; m < 16; m <<= 1) {
                ps[reg][h] += __shfl_xor(ps[reg][h], m);
                pd[reg][h] += __shfl_xor(pd[reg][h], m);
            }
    if (i16 < HEADS) {
        int h = i16;
#pragma unroll
        for (int reg = 0; reg < 4; reg++) {
            long row = rb + reg;
            if (row < nrows) {
                float pv = 0.f, dv = 0.f;
#pragma unroll
                for (int hh = 0; hh < HEADS; hh++) { if (hh == h) { pv = ps[reg][hh]; dv = pd[reg][hh]; } }
                as_[row * HEADS + h] = pv;
                ad_[row * HEADS + h] = dv;
            }
        }
    }
}

// ---------------- fused: in-LDS counting sort (blocks 0..255) | MFMA GEMM1 ----------------
__global__ __launch_bounds__(256) void fused_csr_gemm1_kernel(
    const int* __restrict__ ei, unsigned* __restrict__ priv,
    int* __restrict__ cnt_mtx, int* __restrict__ lofs_mtx,
    const float* __restrict__ A, const __half* __restrict__ Wf1,
    const float* __restrict__ atts, const float* __restrict__ attd,
    __half* __restrict__ H, float* __restrict__ as_, float* __restrict__ ad_, int nrows) {
    __shared__ __align__(16) char smem[21760];
    if (blockIdx.x >= CSRB) {
        gemm_mfma_body<128, 4, float>(blockIdx.x - CSRB, (__half*)smem, A, Wf1, atts, attd,
                                      H, as_, ad_, nrows);
        return;
    }
    int* hist = (int*)smem;
    int* lofs = hist + 1024;
    int* sbuf = lofs + 1024;
    unsigned* ebuf = (unsigned*)(sbuf + 256);
    int tid = threadIdx.x;
    for (int i = tid; i < 1024; i += 256) hist[i] = 0;
    __syncthreads();
    int e0 = blockIdx.x * EPB;
    int dreg[13];
#pragma unroll
    for (int i = 0; i < 13; i++) {
        int e = e0 + i * 256 + tid;
        dreg[i] = (e < e0 + EPB) ? ei[NEDGES + e] : -1;
        if (dreg[i] >= 0) atomicAdd(&hist[dreg[i] >> 6], 1);
    }
    __syncthreads();
    int t4 = tid * 4;
    int a0 = hist[t4], a1 = hist[t4 + 1], a2 = hist[t4 + 2], a3 = hist[t4 + 3];
    int p1 = a0 + a1, p2 = p1 + a2, p3 = p2 + a3;
    sbuf[tid] = p3;
    __syncthreads();
    for (int off = 1; off < 256; off <<= 1) {
        int v = (tid >= off) ? sbuf[tid - off] : 0;
        __syncthreads();
        sbuf[tid] += v;
        __syncthreads();
    }
    int base = (tid > 0) ? sbuf[tid - 1] : 0;
    lofs[t4] = base; lofs[t4 + 1] = base + a0; lofs[t4 + 2] = base + p1; lofs[t4 + 3] = base + p2;
#pragma unroll
    for (int j = 0; j < 4; j++) {
        int i = t4 + j;
        if (i < NB2) {
            cnt_mtx[(long)blockIdx.x * NB2 + i] = hist[i];
            lofs_mtx[(long)blockIdx.x * NB2 + i] = lofs[i];
        }
    }
    hist[t4] = 0; hist[t4 + 1] = 0; hist[t4 + 2] = 0; hist[t4 + 3] = 0;
    __syncthreads();
#pragma unroll
    for (int i = 0; i < 13; i++) {
        if (dreg[i] >= 0) {
            int e = e0 + i * 256 + tid;
            int s = ei[e];
            int b = dreg[i] >> 6;
            int r = atomicAdd(&hist[b], 1);
            ebuf[lofs[b] + r] = (unsigned)s | ((unsigned)(dreg[i] & 63) << 16);
        }
    }
    __syncthreads();
    unsigned* seg = priv + (long)blockIdx.x * EPB;
    for (int i = tid; i < EPB; i += 256) seg[i] = ebuf[i];
}

// ---------------- consumer: rank into LDS, dense dump -> dst-grouped ssrc ----------------
__global__ __launch_bounds__(256) void consumer_kernel(
    const unsigned* __restrict__ priv, const int* __restrict__ cnt_mtx,
    const int* __restrict__ lofs_mtx, int* __restrict__ ssrc,
    int* __restrict__ offs, int* __restrict__ ends) {
    __shared__ int dcnt[64], dbase[64], dcur[64];
    __shared__ unsigned ebuf[BCAP2];
    int b = blockIdx.x, tid = threadIdx.x;
    if (tid < 64) dcnt[tid] = 0;
    int cnt = cnt_mtx[(long)tid * NB2 + b];
    int lof = lofs_mtx[(long)tid * NB2 + b];
    const unsigned* seg = priv + (long)tid * EPB + lof;
    __syncthreads();
    for (int k = 0; k < cnt; k++) {
        unsigned v = seg[k];
        atomicAdd(&dcnt[(v >> 16) & 63], 1);
    }
    __syncthreads();
    if (tid < 64) {
        int v = dcnt[tid], p = v;
#pragma unroll
        for (int off = 1; off < 64; off <<= 1) {
            int u = __shfl_up(p, off);
            if (tid >= off) p += u;
        }
        dbase[tid] = p - v;
        dcur[tid] = p - v;
    }
    __syncthreads();
    for (int k = 0; k < cnt; k++) {
        unsigned v = seg[k];
        int dl = (v >> 16) & 63;
        int r = atomicAdd(&dcur[dl], 1);
        if (r < BCAP2) ebuf[r] = v & 0xFFFFu;
    }
    __syncthreads();
    int obase = b * BCAP2;
    int n = dbase[63] + dcnt[63];
    if (n > BCAP2) n = BCAP2;
    for (int i = tid; i < n; i += 256) ssrc[obase + i] = (int)ebuf[i];
    if (tid < 64) {
        int d = b * 64 + tid;
        if (d < NNODES) {
            int s0 = dbase[tid], e1 = s0 + dcnt[tid];
            if (s0 > BCAP2) s0 = BCAP2;
            if (e1 > BCAP2) e1 = BCAP2;
            offs[d] = obase + s0;
            ends[d] = obase + e1;
        }
    }
}

// ---------------- standalone MFMA GEMM (layer 2, fp16 A) ----------------
template<int NCOL, int HEADS, typename AT>
__global__ __launch_bounds__(256) void gemm_att_kernel(
    const AT* __restrict__ A, const __half* __restrict__ Wf,
    const float* __restrict__ atts, const float* __restrict__ attd,
    __half* __restrict__ H, float* __restrict__ as_, float* __restrict__ ad_,
    int nrows) {
    __shared__ __align__(16) __half Ah[64 * PAH];
    gemm_mfma_body<NCOL, HEADS, AT>(blockIdx.x, Ah, A, Wf, atts, attd, H, as_, ad_, nrows);
}

// ---------------- gather: r18 structure; consume loop = clamped 4-load batches ----------
template<int HEADS, int NCOL, int LRELU, typename OT>
__global__ __launch_bounds__(256) void gather_kernel(
    const int* __restrict__ ssrc, const int* __restrict__ offs,
    const int* __restrict__ ends, const float* __restrict__ as_,
    const float* __restrict__ ad_, const __half* __restrict__ H,
    const float* __restrict__ bias, OT* __restrict__ out, int n) {
    constexpr int CHUNK = 64 / HEADS;   // 16 (L1) or 64 (L2)
    constexpr int LPE = NCOL / 8;       // lanes per row: 16 or 8
    constexpr int EPI = 64 / LPE;       // edges per VMEM instr: 4 or 8
    int wave = (blockIdx.x * blockDim.x + threadIdx.x) >> 6;
    if (wave >= n) return;
    int lane = threadIdx.x & 63;
    int d = wave;
    int sub = lane / LPE;
    int c = (lane % LPE) * 8;
    int hc = (HEADS == 1) ? 0 : (c >> 5);
    int SB = hc * CHUNK;
    int pe = (HEADS == 1) ? lane : (lane % CHUNK);
    int ph = (HEADS == 1) ? 0 : (lane / CHUNK);
    float ad_p = ad_[d * HEADS + ph];
    float acc[8];
#pragma unroll
    for (int i = 0; i < 8; i++) acc[i] = 0.f;
    float dsum = 0.f;
    int start = offs[d], end = ends[d];

    int base = start;
    int m = end - base; if (m > CHUNK) m = CHUNK;
    int sv = 0; float wv = 0.f;
    if (m > 0) {
        if (pe < m) {
            sv = ssrc[base + pe];
            wv = __expf(lrelu(as_[sv * HEADS + ph] + ad_p));
        }
        dsum += wv;
    }
    while (m > 0) {
        int nbase = base + CHUNK;
        int nm = end - nbase; if (nm > CHUNK) nm = CHUNK;
        int svn = 0;
        if (nm > 0 && pe < nm) svn = ssrc[nbase + pe];   // prefetch next chunk's indices
        // consume current chunk: batches of 4 clamped loads + masked weights
        for (int i = 0; i < m; i += 4 * EPI) {
            int i0 = i + sub, i1 = i + EPI + sub, i2 = i + 2 * EPI + sub, i3 = i + 3 * EPI + sub;
            int c0 = i0 < m ? i0 : m - 1;
            int c1 = i1 < m ? i1 : m - 1;
            int c2 = i2 < m ? i2 : m - 1;
            int c3 = i3 < m ? i3 : m - 1;
            int s0 = __shfl(sv, SB + c0);
            int s1 = __shfl(sv, SB + c1);
            int s2 = __shfl(sv, SB + c2);
            int s3 = __shfl(sv, SB + c3);
            uint4 v0 = *(const uint4*)&H[(long)s0 * NCOL + c];
            uint4 v1 = *(const uint4*)&H[(long)s1 * NCOL + c];
            uint4 v2 = *(const uint4*)&H[(long)s2 * NCOL + c];
            uint4 v3 = *(const uint4*)&H[(long)s3 * NCOL + c];
            float w0 = __shfl(wv, SB + c0); if (i0 >= m) w0 = 0.f;
            float w1 = __shfl(wv, SB + c1); if (i1 >= m) w1 = 0.f;
            float w2 = __shfl(wv, SB + c2); if (i2 >= m) w2 = 0.f;
            float w3 = __shfl(wv, SB + c3); if (i3 >= m) w3 = 0.f;
            fmamix8(acc, v0, w0); fmamix8(acc, v1, w1);
            fmamix8(acc, v2, w2); fmamix8(acc, v3, w3);
        }
        if (nm <= 0) break;
        float wvn = 0.f;
        if (pe < nm) wvn = __expf(lrelu(as_[svn * HEADS + ph] + ad_p));
        dsum += wvn;
        sv = svn; wv = wvn; m = nm; base = nbase;
    }

    if (HEADS == 1) {
#pragma unroll
        for (int msk = 1; msk < 64; msk <<= 1) dsum += __shfl_xor(dsum, msk);
    } else {
#pragma unroll
        for (int msk = 1; msk < 16; msk <<= 1) dsum += __shfl_xor(dsum, msk);
        dsum = __shfl(dsum, SB);
    }
#pragma unroll
    for (int msk = LPE; msk < 64; msk <<= 1) {
#pragma unroll
        for (int i = 0; i < 8; i++) acc[i] += __shfl_xor(acc[i], msk);
    }
    {
        float wself = __expf(lrelu(as_[d * HEADS + hc] + ad_[d * HEADS + hc]));
        dsum += wself;
        uint4 vs = *(const uint4*)&H[(long)d * NCOL + c];
        fmamix8(acc, vs, wself);
    }
    float inv = 1.f / (dsum + 1e-16f);
    if (lane < LPE) {
        float r[8];
#pragma unroll
        for (int i = 0; i < 8; i++) {
            r[i] = acc[i] * inv + bias[c + i];
            if (LRELU) r[i] = lrelu(r[i]);
        }
        if constexpr (sizeof(OT) == 2) {
            __half2 q0 = __floats2half2_rn(r[0], r[1]);
            __half2 q1 = __floats2half2_rn(r[2], r[3]);
            __half2 q2 = __floats2half2_rn(r[4], r[5]);
            __half2 q3 = __floats2half2_rn(r[6], r[7]);
            uint4 pk = make_uint4(*(unsigned*)&q0, *(unsigned*)&q1, *(unsigned*)&q2, *(unsigned*)&q3);
            *(uint4*)&out[(long)d * NCOL + c] = pk;
        } else {
            *(float4*)&out[(long)d * NCOL + c] = make_float4(r[0], r[1], r[2], r[3]);
            *(float4*)&out[(long)d * NCOL + c + 4] = make_float4(r[4], r[5], r[6], r[7]);
        }
    }
}

static inline int nblk(long total) { return (int)((total + 255) / 256); }

extern "C" void kernel_launch(void* const* d_in, const int* in_sizes, int n_in,
                              void* d_out, int out_size, void* d_ws, size_t ws_size,
                              hipStream_t stream) {
    const float* x    = (const float*)d_in[0];
    const int*   ei   = (const int*)d_in[1];   // [2, NEDGES]
    const float* W1   = (const float*)d_in[2];
    const float* as1w = (const float*)d_in[3];
    const float* ad1w = (const float*)d_in[4];
    const float* b1   = (const float*)d_in[5];
    const float* W2   = (const float*)d_in[6];
    const float* as2w = (const float*)d_in[7];
    const float* ad2w = (const float*)d_in[8];
    const float* b2   = (const float*)d_in[9];
    float* out = (float*)d_out;

    char* wsb = (char*)d_ws;
    size_t o = 0;
    __half* h1    = (__half*)(wsb + o); o += (size_t)NNODES * 128 * 2;   // 12.8 MB; h2 aliases
    __half* x2h   = (__half*)(wsb + o); o += (size_t)NNODES * 128 * 2;   // 12.8 MB
    float* a_src1 = (float*)(wsb + o);  o += (size_t)NNODES * 4 * 4;
    float* a_dst1 = (float*)(wsb + o);  o += (size_t)NNODES * 4 * 4;
    float* a_src2 = (float*)(wsb + o);  o += (size_t)NNODES * 4;
    float* a_dst2 = (float*)(wsb + o);  o += (size_t)NNODES * 4;
    int* offs    = (int*)(wsb + o); o += (size_t)NNODES * 4;
    int* ends    = (int*)(wsb + o); o += (size_t)NNODES * 4;
    int* ssrc    = (int*)(wsb + o); o += (size_t)NB2 * BCAP2 * 4;        // 4.0 MB
    unsigned* priv = (unsigned*)(wsb + o); o += (size_t)CSRB * EPB * 4;  // 3.2 MB
    int* cnt_mtx  = (int*)(wsb + o); o += (size_t)CSRB * NB2 * 4;        // 0.8 MB
    int* lofs_mtx = (int*)(wsb + o); o += (size_t)CSRB * NB2 * 4;        // 0.8 MB
    __half* Wf1  = (__half*)(wsb + o); o += (size_t)2048 * 8 * 2;        // 32 KB
    __half* Wf2  = (__half*)(wsb + o); o += (size_t)1024 * 8 * 2;        // 16 KB
    __half* h2 = h1;

    const int GB = (NNODES + 63) / 64;     // 782

    // ---- W -> fragment-layout f16 (one-time) ----
    wconv_kernel<<<12, 256, 0, stream>>>(W1, W2, Wf1, Wf2);

    // ---- CSR build (in-LDS sort, dense dump) + MFMA GEMM1, fused ----
    fused_csr_gemm1_kernel<<<CSRB + GB, 256, 0, stream>>>(
        ei, priv, cnt_mtx, lofs_mtx, x, Wf1, as1w, ad1w, h1, a_src1, a_dst1, NNODES);
    consumer_kernel<<<NB2, 256, 0, stream>>>(priv, cnt_mtx, lofs_mtx, ssrc, offs, ends);

    // ---- layer 1 gather (fp16 output) ----
    gather_kernel<4, 128, 1, __half><<<nblk((long)NNODES * 64), 256, 0, stream>>>(
        ssrc, offs, ends, a_src1, a_dst1, h1, b1, x2h, NNODES);

    // ---- layer 2 (fp16 A) ----
    gemm_att_kernel<64, 1, __half><<<GB, 256, 0, stream>>>(
        x2h, Wf2, as2w, ad2w, h2, a_src2, a_dst2, NNODES);
    gather_kernel<1, 64, 0, float><<<nblk((long)NNODES * 64), 256, 0, stream>>>(
        ssrc, offs, ends, a_src2, a_dst2, h2, b2, out, NNODES);
}